// Round 1
// baseline (4186.766 us; speedup 1.0000x reference)
//
#include <hip/hip_runtime.h>
#include <hip/hip_bf16.h>

constexpr int N = 16384;   // points
constexpr int KNN = 10;
constexpr int CF = 64;     // feature channels per edgeconv

#define FBIG 1e30f

// ---------- top-k insert (replace-max) ----------
#define TOPK_INSERT(dval, jval)                                            \
  if ((dval) < bmax) {                                                     \
    float mv = bd[0]; int slot = 0;                                        \
    _Pragma("unroll") for (int s_ = 1; s_ < 10; ++s_)                      \
      if (bd[s_] > mv) { mv = bd[s_]; slot = s_; }                         \
    _Pragma("unroll") for (int s_ = 0; s_ < 10; ++s_)                      \
      if (slot == s_) { bd[s_] = (dval); bi[s_] = (jval); }                \
    bmax = bd[0];                                                          \
    _Pragma("unroll") for (int s_ = 1; s_ < 10; ++s_)                      \
      bmax = fmaxf(bmax, bd[s_]);                                          \
  }

// ---------- pack x (3ch) into float4 with sq norm ----------
__global__ __launch_bounds__(256) void pack3_kernel(const float* __restrict__ X,
                                                    float4* __restrict__ xp) {
  int i = blockIdx.x * 256 + threadIdx.x;
  float x0 = X[3 * i], x1 = X[3 * i + 1], x2 = X[3 * i + 2];
  float s = fmaf(x0, x0, fmaf(x1, x1, x2 * x2));
  xp[i] = make_float4(x0, x1, x2, s);
}

// ---------- sq norms for 64-ch features ----------
__global__ __launch_bounds__(256) void sqnorm_kernel(const float* __restrict__ X,
                                                     float* __restrict__ sq) {
  int i = blockIdx.x * 256 + threadIdx.x;
  const float* r = X + (size_t)i * CF;
  float s = 0.f;
#pragma unroll
  for (int c = 0; c < CF; ++c) s = fmaf(r[c], r[c], s);  // same order as GEMM k-accum
  sq[i] = s;
}

// ---------- kNN for C=3 (layer 1). grid = 64 rowgroups x 4 col-quarters ----------
__global__ __launch_bounds__(256) void knn3_kernel(const float4* __restrict__ xp,
                                                   float* __restrict__ dpart,
                                                   int* __restrict__ ipart) {
  const int tid = threadIdx.x;
  const int bid = blockIdx.x;
  const int rg = bid >> 2;
  const int q = bid & 3;
  const int row = rg * 256 + tid;
  const float4 me = xp[row];

  float bd[10]; int bi[10];
#pragma unroll
  for (int s = 0; s < 10; ++s) { bd[s] = FBIG; bi[s] = -1; }
  float bmax = FBIG;

  const int jb = q * 4096;
#pragma unroll 1
  for (int c = 0; c < 4096; c += 4) {
    float4 o0 = xp[jb + c + 0];
    float4 o1 = xp[jb + c + 1];
    float4 o2 = xp[jb + c + 2];
    float4 o3 = xp[jb + c + 3];
    float d0 = fmaf(-2.f, fmaf(me.x, o0.x, fmaf(me.y, o0.y, me.z * o0.z)), me.w + o0.w);
    float d1 = fmaf(-2.f, fmaf(me.x, o1.x, fmaf(me.y, o1.y, me.z * o1.z)), me.w + o1.w);
    float d2 = fmaf(-2.f, fmaf(me.x, o2.x, fmaf(me.y, o2.y, me.z * o2.z)), me.w + o2.w);
    float d3 = fmaf(-2.f, fmaf(me.x, o3.x, fmaf(me.y, o3.y, me.z * o3.z)), me.w + o3.w);
    TOPK_INSERT(d0, jb + c + 0);
    TOPK_INSERT(d1, jb + c + 1);
    TOPK_INSERT(d2, jb + c + 2);
    TOPK_INSERT(d3, jb + c + 3);
  }

  float* dp = dpart + ((size_t)q * N + row) * 10;
  int* ip = ipart + ((size_t)q * N + row) * 10;
#pragma unroll
  for (int s = 0; s < 10; ++s) { dp[s] = bd[s]; ip[s] = bi[s]; }
}

// ---------- kNN for C=64 via fused tiled GEMM + top-k ----------
// grid = 128 rowgroups x 2 col-halves = 256 blocks of 256 threads.
// Block: 128 rows x (64 tiles of 128 cols). Thread frag: 8x8 split as {4tr..+3,64+4tr..+3} x {4tc..+3,64+4tc..+3}.
__global__ __launch_bounds__(256) void knn64_kernel(const float* __restrict__ X,
                                                    const float* __restrict__ sq,
                                                    float* __restrict__ dpart,
                                                    int* __restrict__ ipart) {
  __shared__ float As[64 * 132];   // [k][row]
  __shared__ float Bs[64 * 132];   // [k][col]
  __shared__ float Ds[128 * 132];  // [row][col]
  __shared__ float sqj_s[128];

  const int tid = threadIdx.x;
  const int bid = blockIdx.x;
  const int rg = bid >> 1;
  const int half = bid & 1;
  const int row_base = rg * 128;
  const int col_base = half * 8192;
  const int tr = tid >> 4;  // 0..15
  const int tc = tid & 15;  // 0..15

  // stage A once (coalesced global float4 reads, transposed LDS store)
  {
    const float4* X4 = (const float4*)(X + (size_t)row_base * CF);
#pragma unroll
    for (int i = 0; i < 8; ++i) {
      int flat = i * 256 + tid;      // 0..2047
      int r = flat >> 4;             // 0..127
      int k4 = (flat & 15) << 2;
      float4 v = X4[flat];
      As[(k4 + 0) * 132 + r] = v.x;
      As[(k4 + 1) * 132 + r] = v.y;
      As[(k4 + 2) * 132 + r] = v.z;
      As[(k4 + 3) * 132 + r] = v.w;
    }
  }

  float sqi_r[8];
#pragma unroll
  for (int i = 0; i < 4; ++i) {
    sqi_r[i] = sq[row_base + 4 * tr + i];
    sqi_r[4 + i] = sq[row_base + 64 + 4 * tr + i];
  }

  float bd[10]; int bi[10];
#pragma unroll
  for (int s = 0; s < 10; ++s) { bd[s] = FBIG; bi[s] = -1; }
  float bmax = FBIG;

  for (int t = 0; t < 64; ++t) {
    const int ctile = col_base + t * 128;
    __syncthreads();  // prior scan (Ds) and prior GEMM (Bs) complete
    {
      const float4* X4 = (const float4*)(X + (size_t)ctile * CF);
#pragma unroll
      for (int i = 0; i < 8; ++i) {
        int flat = i * 256 + tid;
        int cc = flat >> 4;
        int k4 = (flat & 15) << 2;
        float4 v = X4[flat];
        Bs[(k4 + 0) * 132 + cc] = v.x;
        Bs[(k4 + 1) * 132 + cc] = v.y;
        Bs[(k4 + 2) * 132 + cc] = v.z;
        Bs[(k4 + 3) * 132 + cc] = v.w;
      }
      if (tid < 128) sqj_s[tid] = sq[ctile + tid];
    }
    __syncthreads();

    float acc[8][8];
#pragma unroll
    for (int i = 0; i < 8; ++i)
#pragma unroll
      for (int j = 0; j < 8; ++j) acc[i][j] = 0.f;

#pragma unroll 4
    for (int k = 0; k < 64; ++k) {
      float4 a0 = *(const float4*)&As[k * 132 + 4 * tr];
      float4 a1 = *(const float4*)&As[k * 132 + 64 + 4 * tr];
      float4 b0 = *(const float4*)&Bs[k * 132 + 4 * tc];
      float4 b1 = *(const float4*)&Bs[k * 132 + 64 + 4 * tc];
      float a[8] = {a0.x, a0.y, a0.z, a0.w, a1.x, a1.y, a1.z, a1.w};
      float b[8] = {b0.x, b0.y, b0.z, b0.w, b1.x, b1.y, b1.z, b1.w};
#pragma unroll
      for (int i = 0; i < 8; ++i)
#pragma unroll
        for (int j = 0; j < 8; ++j) acc[i][j] = fmaf(a[i], b[j], acc[i][j]);
    }

    // epilogue: dist = sq_i + sq_j - 2*dot  -> Ds
#pragma unroll
    for (int i = 0; i < 8; ++i) {
      int ra = (i < 4) ? (4 * tr + i) : (64 + 4 * tr + (i - 4));
      float si = sqi_r[i];
      float4 w0, w1;
      w0.x = fmaf(-2.f, acc[i][0], si + sqj_s[4 * tc + 0]);
      w0.y = fmaf(-2.f, acc[i][1], si + sqj_s[4 * tc + 1]);
      w0.z = fmaf(-2.f, acc[i][2], si + sqj_s[4 * tc + 2]);
      w0.w = fmaf(-2.f, acc[i][3], si + sqj_s[4 * tc + 3]);
      w1.x = fmaf(-2.f, acc[i][4], si + sqj_s[64 + 4 * tc + 0]);
      w1.y = fmaf(-2.f, acc[i][5], si + sqj_s[64 + 4 * tc + 1]);
      w1.z = fmaf(-2.f, acc[i][6], si + sqj_s[64 + 4 * tc + 2]);
      w1.w = fmaf(-2.f, acc[i][7], si + sqj_s[64 + 4 * tc + 3]);
      *(float4*)&Ds[ra * 132 + 4 * tc] = w0;
      *(float4*)&Ds[ra * 132 + 64 + 4 * tc] = w1;
    }
    __syncthreads();

    if (tid < 128) {
      const float* drow = &Ds[tid * 132];
#pragma unroll 1
      for (int c = 0; c < 128; c += 4) {
        float4 dv = *(const float4*)&drow[c];
        TOPK_INSERT(dv.x, ctile + c + 0);
        TOPK_INSERT(dv.y, ctile + c + 1);
        TOPK_INSERT(dv.z, ctile + c + 2);
        TOPK_INSERT(dv.w, ctile + c + 3);
      }
    }
  }

  if (tid < 128) {
    int row = row_base + tid;
    float* dp = dpart + ((size_t)half * N + row) * 10;
    int* ip = ipart + ((size_t)half * N + row) * 10;
#pragma unroll
    for (int s = 0; s < 10; ++s) { dp[s] = bd[s]; ip[s] = bi[s]; }
  }
}

// ---------- merge S partial top-10 lists per row ----------
template <int S>
__global__ __launch_bounds__(256) void merge_kernel(const float* __restrict__ dpart,
                                                    const int* __restrict__ ipart,
                                                    int* __restrict__ idx_out) {
  const int row = blockIdx.x * 256 + threadIdx.x;
  float d[S * 10]; int id_[S * 10];
#pragma unroll
  for (int p = 0; p < S; ++p)
#pragma unroll
    for (int s = 0; s < 10; ++s) {
      d[p * 10 + s] = dpart[((size_t)p * N + row) * 10 + s];
      id_[p * 10 + s] = ipart[((size_t)p * N + row) * 10 + s];
    }
#pragma unroll
  for (int t = 0; t < 10; ++t) {
    float dm = d[0]; int im = id_[0]; int slot = 0;
#pragma unroll
    for (int e = 1; e < S * 10; ++e) {
      bool better = (d[e] < dm) || (d[e] == dm && id_[e] < im);
      if (better) { dm = d[e]; im = id_[e]; slot = e; }
    }
    idx_out[(size_t)row * 10 + t] = im;
#pragma unroll
    for (int e = 0; e < S * 10; ++e)
      if (e == slot) d[e] = FBIG;
  }
}

// ---------- u = x*W_bot ; v = x*(W_top - W_bot) + b ----------
__global__ __launch_bounds__(256) void uv_kernel(const float* __restrict__ Xf, int CIN,
                                                 const float* __restrict__ W,
                                                 const float* __restrict__ bias,
                                                 float* __restrict__ U, float* __restrict__ V) {
  int tid = threadIdx.x;
  int c = tid & 63, p = tid >> 6;
  int n = blockIdx.x * 4 + p;
  const float* xr = Xf + (size_t)n * CIN;
  float vt = 0.f, vb = 0.f;
  for (int m = 0; m < CIN; ++m) {
    float xm = xr[m];
    vt = fmaf(xm, W[m * 64 + c], vt);
    vb = fmaf(xm, W[(CIN + m) * 64 + c], vb);
  }
  U[(size_t)n * 64 + c] = vb;
  V[(size_t)n * 64 + c] = vt - vb + bias[c];
}

// ---------- BN batch stats: accum[0:64]=sum h, accum[64:128]=sum h^2 ----------
__global__ __launch_bounds__(256) void stats_kernel(const float* __restrict__ U,
                                                    const float* __restrict__ V,
                                                    const int* __restrict__ idx,
                                                    float* __restrict__ accum) {
  int tid = threadIdx.x;
  int c = tid & 63, p = tid >> 6;
  int base = blockIdx.x * 256;  // 64 blocks
  float s = 0.f, s2 = 0.f;
  for (int ch = 0; ch < 64; ++ch) {
    int n = base + ch * 4 + p;
    float vn = V[(size_t)n * 64 + c];
    const int* in_ = idx + (size_t)n * 10;
#pragma unroll
    for (int k = 0; k < 10; ++k) {
      float h = vn + U[(size_t)in_[k] * 64 + c];
      s += h;
      s2 = fmaf(h, h, s2);
    }
  }
  __shared__ float red[256], red2[256];
  red[tid] = s; red2[tid] = s2;
  __syncthreads();
  if (tid < 64) {
    float ts = red[tid] + red[64 + tid] + red[128 + tid] + red[192 + tid];
    float t2 = red2[tid] + red2[64 + tid] + red2[128 + tid] + red2[192 + tid];
    atomicAdd(&accum[tid], ts);
    atomicAdd(&accum[64 + tid], t2);
  }
}

__global__ void bnfin_kernel(const float* __restrict__ accum,
                             const float* __restrict__ gamma,
                             const float* __restrict__ beta,
                             float* __restrict__ scale, float* __restrict__ shift) {
  int c = threadIdx.x;  // 64
  float inv = 1.f / (float)(N * KNN);
  float mu = accum[c] * inv;
  float var = accum[64 + c] * inv - mu * mu;
  float sc = gamma[c] * rsqrtf(var + 1e-5f);
  scale[c] = sc;
  shift[c] = fmaf(-mu, sc, beta[c]);
}

// ---------- apply (BN) + ReLU + max over k ----------
__global__ __launch_bounds__(256) void apply_kernel(const float* __restrict__ U,
                                                    const float* __restrict__ V,
                                                    const int* __restrict__ idx,
                                                    const float* __restrict__ scale,
                                                    const float* __restrict__ shift,
                                                    int use_bn, float* __restrict__ Fout) {
  int tid = threadIdx.x;
  int c = tid & 63, p = tid >> 6;
  int n = blockIdx.x * 4 + p;
  float sc = use_bn ? scale[c] : 1.f;
  float sh = use_bn ? shift[c] : 0.f;
  float vn = V[(size_t)n * 64 + c];
  const int* in_ = idx + (size_t)n * 10;
  float m = 0.f;  // max of relu'd values is >= 0
#pragma unroll
  for (int k = 0; k < 10; ++k) {
    float h = vn + U[(size_t)in_[k] * 64 + c];
    m = fmaxf(m, fmaf(h, sc, sh));
  }
  Fout[(size_t)n * 64 + c] = m;
}

// ---------- segment max pooling -> P[64][256] ----------
__global__ __launch_bounds__(256) void pool_kernel(const float* __restrict__ f1,
                                                   const float* __restrict__ f2,
                                                   const float* __restrict__ f3,
                                                   const float* __restrict__ f4,
                                                   const int* __restrict__ n_pts,
                                                   float* __restrict__ P) {
  int b = blockIdx.x;   // 64 segments
  int c = threadIdx.x;  // 256 = 4 feats x 64 ch
  int off = 0;
  for (int i = 0; i < b; ++i) off += n_pts[i];
  int cnt = n_pts[b];
  const float* f = (c < 64) ? f1 : (c < 128) ? f2 : (c < 192) ? f3 : f4;
  int ch = c & 63;
  float m = -3.4e38f;
  for (int t = 0; t < cnt; ++t) m = fmaxf(m, f[(size_t)(off + t) * 64 + ch]);
  P[b * 256 + c] = m;
}

// ---------- head: tanh(P@Wp + bp), L2 normalize rows ----------
__global__ __launch_bounds__(128) void head_kernel(const float* __restrict__ P,
                                                   const float* __restrict__ Wp,
                                                   const float* __restrict__ bp,
                                                   float* __restrict__ out) {
  int b = blockIdx.x;   // 64
  int c = threadIdx.x;  // 128
  __shared__ float ps[256];
  ps[c] = P[b * 256 + c];
  ps[128 + c] = P[b * 256 + 128 + c];
  __syncthreads();
  float acc = bp[c];
  for (int m = 0; m < 256; ++m) acc = fmaf(ps[m], Wp[m * 128 + c], acc);
  float t = tanhf(acc);
  __shared__ float red[128];
  red[c] = t * t;
  __syncthreads();
  for (int s = 64; s > 0; s >>= 1) {
    if (c < s) red[c] += red[c + s];
    __syncthreads();
  }
  float nrm = sqrtf(red[0]);
  out[b * 128 + c] = t / (nrm + 1e-9f);
}

extern "C" void kernel_launch(void* const* d_in, const int* in_sizes, int n_in,
                              void* d_out, int out_size, void* d_ws, size_t ws_size,
                              hipStream_t stream) {
  const float* x = (const float*)d_in[0];
  const int* n_pts = (const int*)d_in[1];
  const float* W1 = (const float*)d_in[2];
  const float* b1 = (const float*)d_in[3];
  const float* g1 = (const float*)d_in[4];
  const float* be1 = (const float*)d_in[5];
  const float* W2 = (const float*)d_in[6];
  const float* b2 = (const float*)d_in[7];
  const float* W3 = (const float*)d_in[8];
  const float* b3 = (const float*)d_in[9];
  const float* g3 = (const float*)d_in[10];
  const float* be3 = (const float*)d_in[11];
  const float* W4 = (const float*)d_in[12];
  const float* b4 = (const float*)d_in[13];
  const float* Wp = (const float*)d_in[14];
  const float* bp = (const float*)d_in[15];
  float* out = (float*)d_out;

  // workspace carve (~31.5 MB)
  char* w = (char*)d_ws;
  auto alloc = [&](size_t bytes) {
    char* p = w;
    w += (bytes + 255) & ~(size_t)255;
    return p;
  };
  const size_t FS = (size_t)N * 64 * 4;
  float* f1 = (float*)alloc(FS);
  float* f2 = (float*)alloc(FS);
  float* f3 = (float*)alloc(FS);
  float* f4 = (float*)alloc(FS);
  float* Ub = (float*)alloc(FS);
  float* Vb = (float*)alloc(FS);
  float4* xp = (float4*)alloc((size_t)N * 16);
  float* sqb = (float*)alloc((size_t)N * 4);
  float* dpartf = (float*)alloc((size_t)4 * N * 10 * 4);
  int* iparti = (int*)alloc((size_t)4 * N * 10 * 4);
  int* idxb = (int*)alloc((size_t)N * 10 * 4);
  float* accum = (float*)alloc(512);
  float* scaleb = (float*)alloc(256);
  float* shiftb = (float*)alloc(256);
  float* Pb = (float*)alloc((size_t)64 * 256 * 4);
  (void)ws_size; (void)n_in; (void)in_sizes; (void)out_size;

  auto run_layer = [&](const float* fin, int cin, const float* W, const float* b,
                       const float* g, const float* be, int use_bn, float* fout) {
    if (cin == 3) {
      pack3_kernel<<<N / 256, 256, 0, stream>>>(fin, xp);
      knn3_kernel<<<256, 256, 0, stream>>>(xp, dpartf, iparti);
      merge_kernel<4><<<N / 256, 256, 0, stream>>>(dpartf, iparti, idxb);
    } else {
      sqnorm_kernel<<<N / 256, 256, 0, stream>>>(fin, sqb);
      knn64_kernel<<<256, 256, 0, stream>>>(fin, sqb, dpartf, iparti);
      merge_kernel<2><<<N / 256, 256, 0, stream>>>(dpartf, iparti, idxb);
    }
    uv_kernel<<<N / 4, 256, 0, stream>>>(fin, cin, W, b, Ub, Vb);
    if (use_bn) {
      hipMemsetAsync(accum, 0, 512, stream);
      stats_kernel<<<64, 256, 0, stream>>>(Ub, Vb, idxb, accum);
      bnfin_kernel<<<1, 64, 0, stream>>>(accum, g, be, scaleb, shiftb);
    }
    apply_kernel<<<N / 4, 256, 0, stream>>>(Ub, Vb, idxb, scaleb, shiftb, use_bn, fout);
  };

  run_layer(x, 3, W1, b1, g1, be1, 1, f1);
  run_layer(f1, 64, W2, b2, nullptr, nullptr, 0, f2);
  run_layer(f2, 64, W3, b3, g3, be3, 1, f3);
  run_layer(f3, 64, W4, b4, nullptr, nullptr, 0, f4);
  pool_kernel<<<64, 256, 0, stream>>>(f1, f2, f3, f4, n_pts, Pb);
  head_kernel<<<64, 128, 0, stream>>>(Pb, Wp, bp, out);
}

// Round 2
// 2752.074 us; speedup vs baseline: 1.5213x; 1.5213x over previous
//
#include <hip/hip_runtime.h>
#include <hip/hip_bf16.h>

constexpr int N = 16384;   // points
constexpr int KNN = 10;
constexpr int CF = 64;     // feature channels per edgeconv

#define FBIG 1e30f

typedef __attribute__((ext_vector_type(8))) __bf16 bfv8;
typedef __attribute__((ext_vector_type(4))) float f32x4;

// ---------- top-k insert (replace-max) ----------
#define TOPK_INSERT(dval, jval)                                            \
  if ((dval) < bmax) {                                                     \
    float mv = bd[0]; int slot = 0;                                        \
    _Pragma("unroll") for (int s_ = 1; s_ < 10; ++s_)                      \
      if (bd[s_] > mv) { mv = bd[s_]; slot = s_; }                         \
    _Pragma("unroll") for (int s_ = 0; s_ < 10; ++s_)                      \
      if (slot == s_) { bd[s_] = (dval); bi[s_] = (jval); }                \
    bmax = bd[0];                                                          \
    _Pragma("unroll") for (int s_ = 1; s_ < 10; ++s_)                      \
      bmax = fmaxf(bmax, bd[s_]);                                          \
  }

// ---------- pack x (3ch) into float4 with sq norm ----------
__global__ __launch_bounds__(256) void pack3_kernel(const float* __restrict__ X,
                                                    float4* __restrict__ xp) {
  int i = blockIdx.x * 256 + threadIdx.x;
  float x0 = X[3 * i], x1 = X[3 * i + 1], x2 = X[3 * i + 2];
  float s = fmaf(x0, x0, fmaf(x1, x1, x2 * x2));
  xp[i] = make_float4(x0, x1, x2, s);
}

// ---------- sq norms for 64-ch features ----------
__global__ __launch_bounds__(256) void sqnorm_kernel(const float* __restrict__ X,
                                                     float* __restrict__ sq) {
  int i = blockIdx.x * 256 + threadIdx.x;
  const float* r = X + (size_t)i * CF;
  float s = 0.f;
#pragma unroll
  for (int c = 0; c < CF; ++c) s = fmaf(r[c], r[c], s);
  sq[i] = s;
}

// ---------- fp32 -> bf16 hi/lo split (RNE both) ----------
__global__ __launch_bounds__(256) void prep64_kernel(const float* __restrict__ X,
                                                     ushort* __restrict__ Xhi,
                                                     ushort* __restrict__ Xlo) {
  int i = blockIdx.x * 256 + threadIdx.x;  // one float4 per thread
  float4 v = ((const float4*)X)[i];
  float vv[4] = {v.x, v.y, v.z, v.w};
  ushort h[4], lo[4];
#pragma unroll
  for (int k = 0; k < 4; ++k) {
    unsigned u = __float_as_uint(vv[k]);
    unsigned r = (u + 0x7FFFu + ((u >> 16) & 1u)) >> 16;
    h[k] = (ushort)r;
    float hf = __uint_as_float(r << 16);
    float l = vv[k] - hf;
    unsigned ul = __float_as_uint(l);
    unsigned rl = (ul + 0x7FFFu + ((ul >> 16) & 1u)) >> 16;
    lo[k] = (ushort)rl;
  }
  ((ushort4*)Xhi)[i] = make_ushort4(h[0], h[1], h[2], h[3]);
  ((ushort4*)Xlo)[i] = make_ushort4(lo[0], lo[1], lo[2], lo[3]);
}

// ---------- kNN for C=3 (layer 1). grid = 64 rowgroups x 4 col-quarters ----------
__global__ __launch_bounds__(256) void knn3_kernel(const float4* __restrict__ xp,
                                                   float* __restrict__ dpart,
                                                   int* __restrict__ ipart) {
  const int tid = threadIdx.x;
  const int bid = blockIdx.x;
  const int rg = bid >> 2;
  const int q = bid & 3;
  const int row = rg * 256 + tid;
  const float4 me = xp[row];

  float bd[10]; int bi[10];
#pragma unroll
  for (int s = 0; s < 10; ++s) { bd[s] = FBIG; bi[s] = -1; }
  float bmax = FBIG;

  const int jb = q * 4096;
#pragma unroll 1
  for (int c = 0; c < 4096; c += 4) {
    float4 o0 = xp[jb + c + 0];
    float4 o1 = xp[jb + c + 1];
    float4 o2 = xp[jb + c + 2];
    float4 o3 = xp[jb + c + 3];
    float d0 = fmaf(-2.f, fmaf(me.x, o0.x, fmaf(me.y, o0.y, me.z * o0.z)), me.w + o0.w);
    float d1 = fmaf(-2.f, fmaf(me.x, o1.x, fmaf(me.y, o1.y, me.z * o1.z)), me.w + o1.w);
    float d2 = fmaf(-2.f, fmaf(me.x, o2.x, fmaf(me.y, o2.y, me.z * o2.z)), me.w + o2.w);
    float d3 = fmaf(-2.f, fmaf(me.x, o3.x, fmaf(me.y, o3.y, me.z * o3.z)), me.w + o3.w);
    TOPK_INSERT(d0, jb + c + 0);
    TOPK_INSERT(d1, jb + c + 1);
    TOPK_INSERT(d2, jb + c + 2);
    TOPK_INSERT(d3, jb + c + 3);
  }

  float* dp = dpart + ((size_t)q * N + row) * 10;
  int* ip = ipart + ((size_t)q * N + row) * 10;
#pragma unroll
  for (int s = 0; s < 10; ++s) { dp[s] = bd[s]; ip[s] = bi[s]; }
}

// ---------- kNN for C=64 via bf16-split MFMA ----------
// grid = 256 rowgroups x 4 colsplits = 1024 blocks of 256 threads.
// Block: 64 rows (4 waves x one 16-row m-tile) x 4096 cols (32 tiles of 128).
// dist = sq_i + sq_j - 2*(hi.hi + hi.lo + lo.hi)  [drops lo.lo, rel err ~2^-16]
__global__ __launch_bounds__(256, 4) void knn64m_kernel(const ushort* __restrict__ Xhi,
                                                        const ushort* __restrict__ Xlo,
                                                        const float* __restrict__ sq,
                                                        float* __restrict__ dpart,
                                                        int* __restrict__ ipart) {
  __shared__ float Ds[64 * 133];  // [row][col], stride 133: writes <=3-way, scan reads 2-way(free)

  const int tid = threadIdx.x;
  const int w = tid >> 6;        // wave 0..3 (m-tile)
  const int l = tid & 63;        // lane
  const int lp = l & 15;         // point-in-tile (A row / B col / C col)
  const int lk = (l >> 4) * 8;   // k-chunk offset
  const int bid = blockIdx.x;
  const int rg = bid >> 2;
  const int cs = bid & 3;
  const int row_base = rg * 64;
  const int col_base = cs * 4096;

  // A fragments, pinned in registers for the whole kernel
  const int arow = row_base + w * 16 + lp;
  const size_t ao = (size_t)arow * 64 + lk;
  bfv8 ah0 = *(const bfv8*)&Xhi[ao];
  bfv8 ah1 = *(const bfv8*)&Xhi[ao + 32];
  bfv8 al0 = *(const bfv8*)&Xlo[ao];
  bfv8 al1 = *(const bfv8*)&Xlo[ao + 32];

  const int rr = w * 16 + (l >> 4) * 4;  // local row of C reg 0
  float sqi[4];
#pragma unroll
  for (int r = 0; r < 4; ++r) sqi[r] = sq[row_base + rr + r];

  const int srow = tid & 63;  // scan row
  const int sq4 = tid >> 6;   // scan col-quarter

  float bd[10]; int bi[10];
#pragma unroll
  for (int s = 0; s < 10; ++s) { bd[s] = FBIG; bi[s] = -1; }
  float bmax = FBIG;

  for (int t = 0; t < 32; ++t) {
    const int ct = col_base + t * 128;
    __syncthreads();  // Ds free (previous scan done)
#pragma unroll 2
    for (int nt = 0; nt < 8; ++nt) {
      const int bcol = ct + nt * 16 + lp;
      const size_t bo = (size_t)bcol * 64 + lk;
      bfv8 bh0 = *(const bfv8*)&Xhi[bo];
      bfv8 bh1 = *(const bfv8*)&Xhi[bo + 32];
      bfv8 bl0 = *(const bfv8*)&Xlo[bo];
      bfv8 bl1 = *(const bfv8*)&Xlo[bo + 32];
      float sj = sq[bcol];
      f32x4 acc = {0.f, 0.f, 0.f, 0.f};
      acc = __builtin_amdgcn_mfma_f32_16x16x32_bf16(ah0, bh0, acc, 0, 0, 0);
      acc = __builtin_amdgcn_mfma_f32_16x16x32_bf16(ah1, bh1, acc, 0, 0, 0);
      acc = __builtin_amdgcn_mfma_f32_16x16x32_bf16(ah0, bl0, acc, 0, 0, 0);
      acc = __builtin_amdgcn_mfma_f32_16x16x32_bf16(ah1, bl1, acc, 0, 0, 0);
      acc = __builtin_amdgcn_mfma_f32_16x16x32_bf16(al0, bh0, acc, 0, 0, 0);
      acc = __builtin_amdgcn_mfma_f32_16x16x32_bf16(al1, bh1, acc, 0, 0, 0);
      const int dcol = nt * 16 + lp;
#pragma unroll
      for (int r = 0; r < 4; ++r) {
        float dist = fmaf(-2.f, acc[r], sqi[r] + sj);
        Ds[(rr + r) * 133 + dcol] = dist;
      }
    }
    __syncthreads();
    const float* drow = &Ds[srow * 133 + sq4 * 32];
#pragma unroll 1
    for (int j = 0; j < 32; ++j) {
      float dv = drow[j];
      TOPK_INSERT(dv, ct + sq4 * 32 + j);
    }
  }

  // block-level merge of the 4 col-quarter lists per row (reuse Ds as scratch)
  __syncthreads();
  float* md = Ds;                 // [64][40] dists
  int* mi = (int*)(Ds + 2560);    // [64][40] idxs
#pragma unroll
  for (int s = 0; s < 10; ++s) {
    md[srow * 40 + sq4 * 10 + s] = bd[s];
    mi[srow * 40 + sq4 * 10 + s] = bi[s];
  }
  __syncthreads();
  if (tid < 64) {
    const int row = row_base + tid;
    float* dp = dpart + ((size_t)cs * N + row) * 10;
    int* ip = ipart + ((size_t)cs * N + row) * 10;
    float* mdr = &md[tid * 40];
    int* mir = &mi[tid * 40];
    for (int t10 = 0; t10 < 10; ++t10) {
      float dm = FBIG; int im = 0x7fffffff; int slot = 0;
      for (int e = 0; e < 40; ++e) {
        float de = mdr[e]; int ie = mir[e];
        bool better = (de < dm) || (de == dm && ie < im);
        if (better) { dm = de; im = ie; slot = e; }
      }
      dp[t10] = dm; ip[t10] = im;
      mdr[slot] = FBIG;
    }
  }
}

// ---------- merge S partial top-10 lists per row ----------
template <int S>
__global__ __launch_bounds__(256) void merge_kernel(const float* __restrict__ dpart,
                                                    const int* __restrict__ ipart,
                                                    int* __restrict__ idx_out) {
  const int row = blockIdx.x * 256 + threadIdx.x;
  float d[S * 10]; int id_[S * 10];
#pragma unroll
  for (int p = 0; p < S; ++p)
#pragma unroll
    for (int s = 0; s < 10; ++s) {
      d[p * 10 + s] = dpart[((size_t)p * N + row) * 10 + s];
      id_[p * 10 + s] = ipart[((size_t)p * N + row) * 10 + s];
    }
#pragma unroll
  for (int t = 0; t < 10; ++t) {
    float dm = d[0]; int im = id_[0]; int slot = 0;
#pragma unroll
    for (int e = 1; e < S * 10; ++e) {
      bool better = (d[e] < dm) || (d[e] == dm && id_[e] < im);
      if (better) { dm = d[e]; im = id_[e]; slot = e; }
    }
    idx_out[(size_t)row * 10 + t] = im;
#pragma unroll
    for (int e = 0; e < S * 10; ++e)
      if (e == slot) d[e] = FBIG;
  }
}

// ---------- u = x*W_bot ; v = x*(W_top - W_bot) + b ----------
__global__ __launch_bounds__(256) void uv_kernel(const float* __restrict__ Xf, int CIN,
                                                 const float* __restrict__ W,
                                                 const float* __restrict__ bias,
                                                 float* __restrict__ U, float* __restrict__ V) {
  int tid = threadIdx.x;
  int c = tid & 63, p = tid >> 6;
  int n = blockIdx.x * 4 + p;
  const float* xr = Xf + (size_t)n * CIN;
  float vt = 0.f, vb = 0.f;
  for (int m = 0; m < CIN; ++m) {
    float xm = xr[m];
    vt = fmaf(xm, W[m * 64 + c], vt);
    vb = fmaf(xm, W[(CIN + m) * 64 + c], vb);
  }
  U[(size_t)n * 64 + c] = vb;
  V[(size_t)n * 64 + c] = vt - vb + bias[c];
}

// ---------- BN batch stats ----------
__global__ __launch_bounds__(256) void stats_kernel(const float* __restrict__ U,
                                                    const float* __restrict__ V,
                                                    const int* __restrict__ idx,
                                                    float* __restrict__ accum) {
  int tid = threadIdx.x;
  int c = tid & 63, p = tid >> 6;
  int base = blockIdx.x * 256;  // 64 blocks
  float s = 0.f, s2 = 0.f;
  for (int ch = 0; ch < 64; ++ch) {
    int n = base + ch * 4 + p;
    float vn = V[(size_t)n * 64 + c];
    const int* in_ = idx + (size_t)n * 10;
#pragma unroll
    for (int k = 0; k < 10; ++k) {
      float h = vn + U[(size_t)in_[k] * 64 + c];
      s += h;
      s2 = fmaf(h, h, s2);
    }
  }
  __shared__ float red[256], red2[256];
  red[tid] = s; red2[tid] = s2;
  __syncthreads();
  if (tid < 64) {
    float ts = red[tid] + red[64 + tid] + red[128 + tid] + red[192 + tid];
    float t2 = red2[tid] + red2[64 + tid] + red2[128 + tid] + red2[192 + tid];
    atomicAdd(&accum[tid], ts);
    atomicAdd(&accum[64 + tid], t2);
  }
}

__global__ void bnfin_kernel(const float* __restrict__ accum,
                             const float* __restrict__ gamma,
                             const float* __restrict__ beta,
                             float* __restrict__ scale, float* __restrict__ shift) {
  int c = threadIdx.x;  // 64
  float inv = 1.f / (float)(N * KNN);
  float mu = accum[c] * inv;
  float var = accum[64 + c] * inv - mu * mu;
  float sc = gamma[c] * rsqrtf(var + 1e-5f);
  scale[c] = sc;
  shift[c] = fmaf(-mu, sc, beta[c]);
}

// ---------- apply (BN) + ReLU + max over k ----------
__global__ __launch_bounds__(256) void apply_kernel(const float* __restrict__ U,
                                                    const float* __restrict__ V,
                                                    const int* __restrict__ idx,
                                                    const float* __restrict__ scale,
                                                    const float* __restrict__ shift,
                                                    int use_bn, float* __restrict__ Fout) {
  int tid = threadIdx.x;
  int c = tid & 63, p = tid >> 6;
  int n = blockIdx.x * 4 + p;
  float sc = use_bn ? scale[c] : 1.f;
  float sh = use_bn ? shift[c] : 0.f;
  float vn = V[(size_t)n * 64 + c];
  const int* in_ = idx + (size_t)n * 10;
  float m = 0.f;
#pragma unroll
  for (int k = 0; k < 10; ++k) {
    float h = vn + U[(size_t)in_[k] * 64 + c];
    m = fmaxf(m, fmaf(h, sc, sh));
  }
  Fout[(size_t)n * 64 + c] = m;
}

// ---------- segment max pooling -> P[64][256] ----------
__global__ __launch_bounds__(256) void pool_kernel(const float* __restrict__ f1,
                                                   const float* __restrict__ f2,
                                                   const float* __restrict__ f3,
                                                   const float* __restrict__ f4,
                                                   const int* __restrict__ n_pts,
                                                   float* __restrict__ P) {
  int b = blockIdx.x;
  int c = threadIdx.x;
  int off = 0;
  for (int i = 0; i < b; ++i) off += n_pts[i];
  int cnt = n_pts[b];
  const float* f = (c < 64) ? f1 : (c < 128) ? f2 : (c < 192) ? f3 : f4;
  int ch = c & 63;
  float m = -3.4e38f;
  for (int t = 0; t < cnt; ++t) m = fmaxf(m, f[(size_t)(off + t) * 64 + ch]);
  P[b * 256 + c] = m;
}

// ---------- head: tanh(P@Wp + bp), L2 normalize rows ----------
__global__ __launch_bounds__(128) void head_kernel(const float* __restrict__ P,
                                                   const float* __restrict__ Wp,
                                                   const float* __restrict__ bp,
                                                   float* __restrict__ out) {
  int b = blockIdx.x;
  int c = threadIdx.x;
  __shared__ float ps[256];
  ps[c] = P[b * 256 + c];
  ps[128 + c] = P[b * 256 + 128 + c];
  __syncthreads();
  float acc = bp[c];
  for (int m = 0; m < 256; ++m) acc = fmaf(ps[m], Wp[m * 128 + c], acc);
  float t = tanhf(acc);
  __shared__ float red[128];
  red[c] = t * t;
  __syncthreads();
  for (int s = 64; s > 0; s >>= 1) {
    if (c < s) red[c] += red[c + s];
    __syncthreads();
  }
  float nrm = sqrtf(red[0]);
  out[b * 128 + c] = t / (nrm + 1e-9f);
}

extern "C" void kernel_launch(void* const* d_in, const int* in_sizes, int n_in,
                              void* d_out, int out_size, void* d_ws, size_t ws_size,
                              hipStream_t stream) {
  const float* x = (const float*)d_in[0];
  const int* n_pts = (const int*)d_in[1];
  const float* W1 = (const float*)d_in[2];
  const float* b1 = (const float*)d_in[3];
  const float* g1 = (const float*)d_in[4];
  const float* be1 = (const float*)d_in[5];
  const float* W2 = (const float*)d_in[6];
  const float* b2 = (const float*)d_in[7];
  const float* W3 = (const float*)d_in[8];
  const float* b3 = (const float*)d_in[9];
  const float* g3 = (const float*)d_in[10];
  const float* be3 = (const float*)d_in[11];
  const float* W4 = (const float*)d_in[12];
  const float* b4 = (const float*)d_in[13];
  const float* Wp = (const float*)d_in[14];
  const float* bp = (const float*)d_in[15];
  float* out = (float*)d_out;

  char* w = (char*)d_ws;
  auto alloc = [&](size_t bytes) {
    char* p = w;
    w += (bytes + 255) & ~(size_t)255;
    return p;
  };
  const size_t FS = (size_t)N * 64 * 4;
  float* f1 = (float*)alloc(FS);
  float* f2 = (float*)alloc(FS);
  float* f3 = (float*)alloc(FS);
  float* f4 = (float*)alloc(FS);
  float* Ub = (float*)alloc(FS);
  float* Vb = (float*)alloc(FS);
  float4* xp = (float4*)alloc((size_t)N * 16);
  float* sqb = (float*)alloc((size_t)N * 4);
  float* dpartf = (float*)alloc((size_t)4 * N * 10 * 4);
  int* iparti = (int*)alloc((size_t)4 * N * 10 * 4);
  int* idxb = (int*)alloc((size_t)N * 10 * 4);
  float* accum = (float*)alloc(512);
  float* scaleb = (float*)alloc(256);
  float* shiftb = (float*)alloc(256);
  float* Pb = (float*)alloc((size_t)64 * 256 * 4);
  // bf16 hi/lo overlay on Ub/Vb (dead until uv_kernel runs, each layer)
  ushort* Xhi = (ushort*)Ub;
  ushort* Xlo = (ushort*)Vb;
  (void)ws_size; (void)n_in; (void)in_sizes; (void)out_size;

  auto run_layer = [&](const float* fin, int cin, const float* W, const float* b,
                       const float* g, const float* be, int use_bn, float* fout) {
    if (cin == 3) {
      pack3_kernel<<<N / 256, 256, 0, stream>>>(fin, xp);
      knn3_kernel<<<256, 256, 0, stream>>>(xp, dpartf, iparti);
    } else {
      prep64_kernel<<<N * 64 / 4 / 256, 256, 0, stream>>>(fin, Xhi, Xlo);
      sqnorm_kernel<<<N / 256, 256, 0, stream>>>(fin, sqb);
      knn64m_kernel<<<1024, 256, 0, stream>>>(Xhi, Xlo, sqb, dpartf, iparti);
    }
    merge_kernel<4><<<N / 256, 256, 0, stream>>>(dpartf, iparti, idxb);
    uv_kernel<<<N / 4, 256, 0, stream>>>(fin, cin, W, b, Ub, Vb);
    if (use_bn) {
      hipMemsetAsync(accum, 0, 512, stream);
      stats_kernel<<<64, 256, 0, stream>>>(Ub, Vb, idxb, accum);
      bnfin_kernel<<<1, 64, 0, stream>>>(accum, g, be, scaleb, shiftb);
    }
    apply_kernel<<<N / 4, 256, 0, stream>>>(Ub, Vb, idxb, scaleb, shiftb, use_bn, fout);
  };

  run_layer(x, 3, W1, b1, g1, be1, 1, f1);
  run_layer(f1, 64, W2, b2, nullptr, nullptr, 0, f2);
  run_layer(f2, 64, W3, b3, g3, be3, 1, f3);
  run_layer(f3, 64, W4, b4, nullptr, nullptr, 0, f4);
  pool_kernel<<<64, 256, 0, stream>>>(f1, f2, f3, f4, n_pts, Pb);
  head_kernel<<<64, 128, 0, stream>>>(Pb, Wp, bp, out);
}

// Round 4
// 1518.979 us; speedup vs baseline: 2.7563x; 1.8118x over previous
//
#include <hip/hip_runtime.h>
#include <hip/hip_bf16.h>

constexpr int N = 16384;   // points
constexpr int KNN = 10;
constexpr int CF = 64;     // feature channels per edgeconv

#define FBIG 1e30f

typedef __attribute__((ext_vector_type(8))) __bf16 bfv8;
typedef __attribute__((ext_vector_type(4))) float f32x4;

// ---------- top-k insert (replace-max) ----------
#define TOPK_INSERT(dval, jval)                                            \
  if ((dval) < bmax) {                                                     \
    float mv = bd[0]; int slot = 0;                                        \
    _Pragma("unroll") for (int s_ = 1; s_ < 10; ++s_)                      \
      if (bd[s_] > mv) { mv = bd[s_]; slot = s_; }                         \
    _Pragma("unroll") for (int s_ = 0; s_ < 10; ++s_)                      \
      if (slot == s_) { bd[s_] = (dval); bi[s_] = (jval); }                \
    bmax = bd[0];                                                          \
    _Pragma("unroll") for (int s_ = 1; s_ < 10; ++s_)                      \
      bmax = fmaxf(bmax, bd[s_]);                                          \
  }

__device__ inline ushort bf16_rne(float x) {
  unsigned u = __float_as_uint(x);
  return (ushort)((u + 0x7FFFu + ((u >> 16) & 1u)) >> 16);
}
__device__ inline float bf16_to_f(ushort h) { return __uint_as_float(((unsigned)h) << 16); }

// ---------- pack x (3ch) into float4 with sq norm ----------
__global__ __launch_bounds__(256) void pack3_kernel(const float* __restrict__ X,
                                                    float4* __restrict__ xp) {
  int i = blockIdx.x * 256 + threadIdx.x;
  float x0 = X[3 * i], x1 = X[3 * i + 1], x2 = X[3 * i + 2];
  float s = fmaf(x0, x0, fmaf(x1, x1, x2 * x2));
  xp[i] = make_float4(x0, x1, x2, s);
}

// ---------- 64-ch prep: hi at k 0..63, lo at k 64..127 ----------
__global__ __launch_bounds__(256) void prep128_kernel(const float* __restrict__ X,
                                                      ushort* __restrict__ Xp) {
  int i = blockIdx.x * 256 + threadIdx.x;  // one float4 per thread
  int n = i >> 4, k4 = (i & 15) << 2;
  float4 v = ((const float4*)X)[i];
  float vv[4] = {v.x, v.y, v.z, v.w};
  ushort h[4], lo[4];
#pragma unroll
  for (int k = 0; k < 4; ++k) {
    h[k] = bf16_rne(vv[k]);
    lo[k] = bf16_rne(vv[k] - bf16_to_f(h[k]));
  }
  ushort* row = Xp + (size_t)n * 128;
  *(ushort4*)(row + k4) = make_ushort4(h[0], h[1], h[2], h[3]);
  *(ushort4*)(row + 64 + k4) = make_ushort4(lo[0], lo[1], lo[2], lo[3]);
}

// ---------- sq norms for 64-ch features ----------
__global__ __launch_bounds__(256) void sqnorm_kernel(const float* __restrict__ X,
                                                     float* __restrict__ sq) {
  int i = blockIdx.x * 256 + threadIdx.x;
  const float* r = X + (size_t)i * CF;
  float s = 0.f;
#pragma unroll
  for (int c = 0; c < CF; ++c) s = fmaf(r[c], r[c], s);
  sq[i] = s;
}

// ---------- shared epilogue structure constants ----------
// Block: 64 rows x 8192 cols (128 tiles of 64 cols). Wave w = 16-col strip.
// Per-row LDS append buffer; owner lanes (l<16) drain per tile, refresh tau.
// Note: cnt resets every tile and max 64 appends/row/tile, so CAP=96 never overflows.
constexpr int CAP = 96;

// ---------- kNN for C=3, exact fp32 distances (cancellation-sensitive!) ----------
// bf16-split here flips ~20% of rank-10 neighbors (3D d^2 ~1e-3 vs sq ~3) -> must stay fp32.
__global__ __launch_bounds__(256, 2) void knn3c_kernel(const float4* __restrict__ xp,
                                                       float* __restrict__ dpart,
                                                       int* __restrict__ ipart) {
  __shared__ float bufD[64 * 97];
  __shared__ ushort bufI[64 * 98];
  __shared__ float tau[64];
  __shared__ int cnt[64];
  __shared__ float4 rowsS[64];

  const int tid = threadIdx.x;
  const int w = tid >> 6;
  const int l = tid & 63;
  const int lp = l & 15;
  const int g = l >> 4;
  const int bid = blockIdx.x;
  const int row_base = (bid >> 1) * 64;
  const int col_base = (bid & 1) * 8192;

  if (tid < 64) {
    rowsS[tid] = xp[row_base + tid];
    tau[tid] = FBIG;
    cnt[tid] = 0;
  }
  __syncthreads();

  // pin this lane's 16 rows (row = rt*16 + g*4 + r) in registers
  float4 rw[16];
#pragma unroll
  for (int rt = 0; rt < 4; ++rt)
#pragma unroll
    for (int r = 0; r < 4; ++r) rw[rt * 4 + r] = rowsS[rt * 16 + g * 4 + r];

  float bd[10]; int bi[10]; float bmax = FBIG;
#pragma unroll
  for (int s = 0; s < 10; ++s) { bd[s] = FBIG; bi[s] = 0x7ffffff; }

  for (int t = 0; t < 128; ++t) {
    const int lcol = t * 64 + w * 16 + lp;
    const float4 o = xp[col_base + lcol];
    __syncthreads();  // phase2 of t-1 done: tau fresh, cnt reset
#pragma unroll
    for (int rt = 0; rt < 4; ++rt) {
      f32x4 taur = *(const f32x4*)&tau[rt * 16 + g * 4];
#pragma unroll
      for (int r = 0; r < 4; ++r) {
        const float4 m = rw[rt * 4 + r];
        float dot = fmaf(m.x, o.x, fmaf(m.y, o.y, m.z * o.z));
        float d = fmaf(-2.f, dot, m.w + o.w);  // exact same chain as validated knn3
        if (d < taur[r]) {
          int rloc = rt * 16 + g * 4 + r;
          int p = atomicAdd(&cnt[rloc], 1);
          if (p < CAP) {
            bufD[rloc * 97 + p] = d;
            bufI[rloc * 98 + p] = (ushort)lcol;
          }
        }
      }
    }
    __syncthreads();  // appends visible

    if (l < 16) {
      const int rloc = w * 16 + l;
      const int c = cnt[rloc] < CAP ? cnt[rloc] : CAP;
#pragma unroll 1
      for (int j = 0; j < c; ++j) {
        float d = bufD[rloc * 97 + j];
        int ii = (int)bufI[rloc * 98 + j];
        TOPK_INSERT(d, ii);
      }
      cnt[rloc] = 0;
      tau[rloc] = bmax;
    }
  }

  if (l < 16) {
    const int row = row_base + w * 16 + l;
    float* dp = dpart + ((size_t)(bid & 1) * N + row) * 10;
    int* ip = ipart + ((size_t)(bid & 1) * N + row) * 10;
#pragma unroll
    for (int s = 0; s < 10; ++s) { dp[s] = bd[s]; ip[s] = col_base + bi[s]; }
  }
}

// ---------- kNN for C=64 via bf16-split MFMA + threshold-filtered append ----------
// grid = 256 rowgroups x 2 col-halves = 512 blocks of 256 threads.
__global__ __launch_bounds__(256, 2) void knn64c_kernel(const ushort* __restrict__ Xp,
                                                        const float* __restrict__ sq,
                                                        float* __restrict__ dpart,
                                                        int* __restrict__ ipart) {
  __shared__ float bufD[64 * 97];
  __shared__ ushort bufI[64 * 98];
  __shared__ float tau[64];
  __shared__ int cnt[64];

  const int tid = threadIdx.x;
  const int w = tid >> 6;
  const int l = tid & 63;
  const int lp = l & 15;
  const int g = l >> 4;
  const int lk = g * 8;
  const int bid = blockIdx.x;
  const int row_base = (bid >> 1) * 64;
  const int col_base = (bid & 1) * 8192;

  if (tid < 64) { tau[tid] = FBIG; cnt[tid] = 0; }

  // A fragments for all 4 row-tiles, pinned in registers
  bfv8 aH1[4], aH2[4], aL1[4], aL2[4];
#pragma unroll
  for (int rt = 0; rt < 4; ++rt) {
    const size_t ao = (size_t)(row_base + rt * 16 + lp) * 128 + lk;
    aH1[rt] = *(const bfv8*)&Xp[ao];
    aH2[rt] = *(const bfv8*)&Xp[ao + 32];
    aL1[rt] = *(const bfv8*)&Xp[ao + 64];
    aL2[rt] = *(const bfv8*)&Xp[ao + 96];
  }
  float sqi_r[16];
#pragma unroll
  for (int rt = 0; rt < 4; ++rt)
#pragma unroll
    for (int r = 0; r < 4; ++r) sqi_r[rt * 4 + r] = sq[row_base + rt * 16 + g * 4 + r];

  float bd[10]; int bi[10]; float bmax = FBIG;
#pragma unroll
  for (int s = 0; s < 10; ++s) { bd[s] = FBIG; bi[s] = 0x7ffffff; }

  __syncthreads();

  for (int t = 0; t < 128; ++t) {
    const int lcol = t * 64 + w * 16 + lp;
    const int bcol = col_base + lcol;
    const size_t bo = (size_t)bcol * 128 + lk;
    bfv8 bH1 = *(const bfv8*)&Xp[bo];
    bfv8 bH2 = *(const bfv8*)&Xp[bo + 32];
    bfv8 bL1 = *(const bfv8*)&Xp[bo + 64];
    bfv8 bL2 = *(const bfv8*)&Xp[bo + 96];
    float sjv = sq[bcol];

    __syncthreads();  // phase2 of t-1 done

#pragma unroll
    for (int rt = 0; rt < 4; ++rt) {
      f32x4 acc = {0.f, 0.f, 0.f, 0.f};
      acc = __builtin_amdgcn_mfma_f32_16x16x32_bf16(aH1[rt], bH1, acc, 0, 0, 0);
      acc = __builtin_amdgcn_mfma_f32_16x16x32_bf16(aH2[rt], bH2, acc, 0, 0, 0);
      acc = __builtin_amdgcn_mfma_f32_16x16x32_bf16(aH1[rt], bL1, acc, 0, 0, 0);
      acc = __builtin_amdgcn_mfma_f32_16x16x32_bf16(aH2[rt], bL2, acc, 0, 0, 0);
      acc = __builtin_amdgcn_mfma_f32_16x16x32_bf16(aL1[rt], bH1, acc, 0, 0, 0);
      acc = __builtin_amdgcn_mfma_f32_16x16x32_bf16(aL2[rt], bH2, acc, 0, 0, 0);
      f32x4 taur = *(const f32x4*)&tau[rt * 16 + g * 4];
#pragma unroll
      for (int r = 0; r < 4; ++r) {
        float d = fmaf(-2.f, acc[r], sqi_r[rt * 4 + r] + sjv);
        if (d < taur[r]) {
          int rloc = rt * 16 + g * 4 + r;
          int p = atomicAdd(&cnt[rloc], 1);
          if (p < CAP) {
            bufD[rloc * 97 + p] = d;
            bufI[rloc * 98 + p] = (ushort)lcol;
          }
        }
      }
    }
    __syncthreads();  // appends visible

    if (l < 16) {
      const int rloc = w * 16 + l;
      const int c = cnt[rloc] < CAP ? cnt[rloc] : CAP;
#pragma unroll 1
      for (int j = 0; j < c; ++j) {
        float d = bufD[rloc * 97 + j];
        int ii = (int)bufI[rloc * 98 + j];
        TOPK_INSERT(d, ii);
      }
      cnt[rloc] = 0;
      tau[rloc] = bmax;
    }
  }

  if (l < 16) {
    const int row = row_base + w * 16 + l;
    float* dp = dpart + ((size_t)(bid & 1) * N + row) * 10;
    int* ip = ipart + ((size_t)(bid & 1) * N + row) * 10;
#pragma unroll
    for (int s = 0; s < 10; ++s) { dp[s] = bd[s]; ip[s] = col_base + bi[s]; }
  }
}

// ---------- merge S partial top-10 lists per row ----------
template <int S>
__global__ __launch_bounds__(256) void merge_kernel(const float* __restrict__ dpart,
                                                    const int* __restrict__ ipart,
                                                    int* __restrict__ idx_out) {
  const int row = blockIdx.x * 256 + threadIdx.x;
  float d[S * 10]; int id_[S * 10];
#pragma unroll
  for (int p = 0; p < S; ++p)
#pragma unroll
    for (int s = 0; s < 10; ++s) {
      d[p * 10 + s] = dpart[((size_t)p * N + row) * 10 + s];
      id_[p * 10 + s] = ipart[((size_t)p * N + row) * 10 + s];
    }
#pragma unroll
  for (int t = 0; t < 10; ++t) {
    float dm = d[0]; int im = id_[0]; int slot = 0;
#pragma unroll
    for (int e = 1; e < S * 10; ++e) {
      bool better = (d[e] < dm) || (d[e] == dm && id_[e] < im);
      if (better) { dm = d[e]; im = id_[e]; slot = e; }
    }
    idx_out[(size_t)row * 10 + t] = im;
#pragma unroll
    for (int e = 0; e < S * 10; ++e)
      if (e == slot) d[e] = FBIG;
  }
}

// ---------- u = x*W_bot ; v = x*(W_top - W_bot) + b ----------
__global__ __launch_bounds__(256) void uv_kernel(const float* __restrict__ Xf, int CIN,
                                                 const float* __restrict__ W,
                                                 const float* __restrict__ bias,
                                                 float* __restrict__ U, float* __restrict__ V) {
  int tid = threadIdx.x;
  int c = tid & 63, p = tid >> 6;
  int n = blockIdx.x * 4 + p;
  const float* xr = Xf + (size_t)n * CIN;
  float vt = 0.f, vb = 0.f;
  for (int m = 0; m < CIN; ++m) {
    float xm = xr[m];
    vt = fmaf(xm, W[m * 64 + c], vt);
    vb = fmaf(xm, W[(CIN + m) * 64 + c], vb);
  }
  U[(size_t)n * 64 + c] = vb;
  V[(size_t)n * 64 + c] = vt - vb + bias[c];
}

// ---------- BN batch stats ----------
__global__ __launch_bounds__(256) void stats_kernel(const float* __restrict__ U,
                                                    const float* __restrict__ V,
                                                    const int* __restrict__ idx,
                                                    float* __restrict__ accum) {
  int tid = threadIdx.x;
  int c = tid & 63, p = tid >> 6;
  int base = blockIdx.x * 64;  // 256 blocks x 64 points
  float s = 0.f, s2 = 0.f;
  for (int ch = 0; ch < 16; ++ch) {
    int n = base + ch * 4 + p;
    float vn = V[(size_t)n * 64 + c];
    const int* in_ = idx + (size_t)n * 10;
#pragma unroll
    for (int k = 0; k < 10; ++k) {
      float h = vn + U[(size_t)in_[k] * 64 + c];
      s += h;
      s2 = fmaf(h, h, s2);
    }
  }
  __shared__ float red[256], red2[256];
  red[tid] = s; red2[tid] = s2;
  __syncthreads();
  if (tid < 64) {
    float ts = red[tid] + red[64 + tid] + red[128 + tid] + red[192 + tid];
    float t2 = red2[tid] + red2[64 + tid] + red2[128 + tid] + red2[192 + tid];
    atomicAdd(&accum[tid], ts);
    atomicAdd(&accum[64 + tid], t2);
  }
}

__global__ void bnfin_kernel(const float* __restrict__ accum,
                             const float* __restrict__ gamma,
                             const float* __restrict__ beta,
                             float* __restrict__ scale, float* __restrict__ shift) {
  int c = threadIdx.x;  // 64
  float inv = 1.f / (float)(N * KNN);
  float mu = accum[c] * inv;
  float var = accum[64 + c] * inv - mu * mu;
  float sc = gamma[c] * rsqrtf(var + 1e-5f);
  scale[c] = sc;
  shift[c] = fmaf(-mu, sc, beta[c]);
}

// ---------- apply (BN) + ReLU + max over k ----------
__global__ __launch_bounds__(256) void apply_kernel(const float* __restrict__ U,
                                                    const float* __restrict__ V,
                                                    const int* __restrict__ idx,
                                                    const float* __restrict__ scale,
                                                    const float* __restrict__ shift,
                                                    int use_bn, float* __restrict__ Fout) {
  int tid = threadIdx.x;
  int c = tid & 63, p = tid >> 6;
  int n = blockIdx.x * 4 + p;
  float sc = use_bn ? scale[c] : 1.f;
  float sh = use_bn ? shift[c] : 0.f;
  float vn = V[(size_t)n * 64 + c];
  const int* in_ = idx + (size_t)n * 10;
  float m = 0.f;
#pragma unroll
  for (int k = 0; k < 10; ++k) {
    float h = vn + U[(size_t)in_[k] * 64 + c];
    m = fmaxf(m, fmaf(h, sc, sh));
  }
  Fout[(size_t)n * 64 + c] = m;
}

// ---------- segment max pooling, 2-stage ----------
__global__ __launch_bounds__(256) void pool1_kernel(const float* __restrict__ f1,
                                                    const float* __restrict__ f2,
                                                    const float* __restrict__ f3,
                                                    const float* __restrict__ f4,
                                                    const int* __restrict__ n_pts,
                                                    float* __restrict__ Pp) {
  int b = blockIdx.x >> 2;
  int q = blockIdx.x & 3;
  int c = threadIdx.x;
  int off = 0;
  for (int i = 0; i < b; ++i) off += n_pts[i];
  int cnt_ = n_pts[b];
  int s0 = off + (cnt_ * q) / 4;
  int s1 = off + (cnt_ * (q + 1)) / 4;
  const float* f = (c < 64) ? f1 : (c < 128) ? f2 : (c < 192) ? f3 : f4;
  int ch = c & 63;
  float m = -3.4e38f;
  for (int t = s0; t < s1; ++t) m = fmaxf(m, f[(size_t)t * 64 + ch]);
  Pp[((size_t)q * 64 + b) * 256 + c] = m;
}

__global__ __launch_bounds__(256) void pool2_kernel(const float* __restrict__ Pp,
                                                    float* __restrict__ P) {
  int b = blockIdx.x;
  int c = threadIdx.x;
  float m = Pp[(size_t)b * 256 + c];
#pragma unroll
  for (int q = 1; q < 4; ++q) m = fmaxf(m, Pp[((size_t)q * 64 + b) * 256 + c]);
  P[b * 256 + c] = m;
}

// ---------- head: tanh(P@Wp + bp), L2 normalize rows ----------
__global__ __launch_bounds__(128) void head_kernel(const float* __restrict__ P,
                                                   const float* __restrict__ Wp,
                                                   const float* __restrict__ bp,
                                                   float* __restrict__ out) {
  int b = blockIdx.x;
  int c = threadIdx.x;
  __shared__ float ps[256];
  ps[c] = P[b * 256 + c];
  ps[128 + c] = P[b * 256 + 128 + c];
  __syncthreads();
  float acc = bp[c];
  for (int m = 0; m < 256; ++m) acc = fmaf(ps[m], Wp[m * 128 + c], acc);
  float t = tanhf(acc);
  __shared__ float red[128];
  red[c] = t * t;
  __syncthreads();
  for (int s = 64; s > 0; s >>= 1) {
    if (c < s) red[c] += red[c + s];
    __syncthreads();
  }
  float nrm = sqrtf(red[0]);
  out[b * 128 + c] = t / (nrm + 1e-9f);
}

extern "C" void kernel_launch(void* const* d_in, const int* in_sizes, int n_in,
                              void* d_out, int out_size, void* d_ws, size_t ws_size,
                              hipStream_t stream) {
  const float* x = (const float*)d_in[0];
  const int* n_pts = (const int*)d_in[1];
  const float* W1 = (const float*)d_in[2];
  const float* b1 = (const float*)d_in[3];
  const float* g1 = (const float*)d_in[4];
  const float* be1 = (const float*)d_in[5];
  const float* W2 = (const float*)d_in[6];
  const float* b2 = (const float*)d_in[7];
  const float* W3 = (const float*)d_in[8];
  const float* b3 = (const float*)d_in[9];
  const float* g3 = (const float*)d_in[10];
  const float* be3 = (const float*)d_in[11];
  const float* W4 = (const float*)d_in[12];
  const float* b4 = (const float*)d_in[13];
  const float* Wp = (const float*)d_in[14];
  const float* bp = (const float*)d_in[15];
  float* out = (float*)d_out;

  char* w = (char*)d_ws;
  auto alloc = [&](size_t bytes) {
    char* p = w;
    w += (bytes + 255) & ~(size_t)255;
    return p;
  };
  const size_t FS = (size_t)N * 64 * 4;
  float* f1 = (float*)alloc(FS);
  float* f2 = (float*)alloc(FS);
  float* f3 = (float*)alloc(FS);
  float* f4 = (float*)alloc(FS);
  float* Ub = (float*)alloc(FS);   // overlaid: Xp128 (N*128 ushorts = FS bytes)
  float* Vb = (float*)alloc(FS);   // overlaid: xp (N float4 = FS/4)
  float* sqb = (float*)alloc((size_t)N * 4);
  float* dpartf = (float*)alloc((size_t)4 * N * 10 * 4);
  int* iparti = (int*)alloc((size_t)4 * N * 10 * 4);
  int* idxb = (int*)alloc((size_t)N * 10 * 4);
  float* accum = (float*)alloc(512);
  float* scaleb = (float*)alloc(256);
  float* shiftb = (float*)alloc(256);
  float* Pb = (float*)alloc((size_t)64 * 256 * 4);
  float* Ppart = (float*)alloc((size_t)4 * 64 * 256 * 4);
  ushort* Xp128 = (ushort*)Ub;
  float4* xp = (float4*)Vb;
  (void)ws_size; (void)n_in; (void)in_sizes; (void)out_size;

  auto run_layer = [&](const float* fin, int cin, const float* W, const float* b,
                       const float* g, const float* be, int use_bn, float* fout) {
    if (cin == 3) {
      pack3_kernel<<<N / 256, 256, 0, stream>>>(fin, xp);
      knn3c_kernel<<<512, 256, 0, stream>>>(xp, dpartf, iparti);
    } else {
      prep128_kernel<<<N * 64 / 4 / 256, 256, 0, stream>>>(fin, Xp128);
      sqnorm_kernel<<<N / 256, 256, 0, stream>>>(fin, sqb);
      knn64c_kernel<<<512, 256, 0, stream>>>(Xp128, sqb, dpartf, iparti);
    }
    merge_kernel<2><<<N / 256, 256, 0, stream>>>(dpartf, iparti, idxb);
    uv_kernel<<<N / 4, 256, 0, stream>>>(fin, cin, W, b, Ub, Vb);
    if (use_bn) {
      hipMemsetAsync(accum, 0, 512, stream);
      stats_kernel<<<256, 256, 0, stream>>>(Ub, Vb, idxb, accum);
      bnfin_kernel<<<1, 64, 0, stream>>>(accum, g, be, scaleb, shiftb);
    }
    apply_kernel<<<N / 4, 256, 0, stream>>>(Ub, Vb, idxb, scaleb, shiftb, use_bn, fout);
  };

  run_layer(x, 3, W1, b1, g1, be1, 1, f1);
  run_layer(f1, 64, W2, b2, nullptr, nullptr, 0, f2);
  run_layer(f2, 64, W3, b3, g3, be3, 1, f3);
  run_layer(f3, 64, W4, b4, nullptr, nullptr, 0, f4);
  pool1_kernel<<<256, 256, 0, stream>>>(f1, f2, f3, f4, n_pts, Ppart);
  pool2_kernel<<<64, 256, 0, stream>>>(Ppart, Pb);
  head_kernel<<<64, 128, 0, stream>>>(Pb, Wp, bp, out);
}